// Round 1
// baseline (400.617 us; speedup 1.0000x reference)
//
#include <hip/hip_runtime.h>

// Problem constants
#define V_CNT   10475
#define M_A     704
#define N_A     128
#define KB      10
#define D_TOT   270336       // 704*128*3
#define ROW384  384          // 128*3 floats per m-row of a pc row
#define NCHUNK  22           // 704 / MT
#define MT      32           // m-tile in k_pcpass
#define LSTR    388          // LDS row stride (floats): 388%32=4 breaks bank conflicts, %4==0 keeps float4 alignment

// ws layout (float offsets)
#define WS_JJ     0          // 33: Jv[3], JB[3][10]
#define WS_CMEAN  64         // 128
#define WS_MC     192        // 384
#define WS_UT     576        // 384*128 = 49152   (Ut[nc][p], p contiguous)
#define WS_V2T    49728      // 2112*128 = 270336 (V2t[mc][p], p contiguous)
#define WS_TOTAL  320064     // floats (1.28 MB)
#define WS_ZEROF  49728      // zero JJ..Ut (atomically accumulated regions)

// ---------------------------------------------------------------- K1: Jv/JB
__global__ __launch_bounds__(256) void k_jreduce(
    const float* __restrict__ Jr, const float* __restrict__ vt,
    const float* __restrict__ sd, float* __restrict__ JJ) {
  float acc[33];
#pragma unroll
  for (int i = 0; i < 33; ++i) acc[i] = 0.f;
  int v = blockIdx.x * blockDim.x + threadIdx.x;
  if (v < V_CNT) {
    float jr = Jr[v];  // row 0 of J_regressor
#pragma unroll
    for (int c = 0; c < 3; ++c) {
      acc[c] += jr * vt[v * 3 + c];
      const float* sp = sd + ((size_t)v * 3 + c) * KB;
#pragma unroll
      for (int k = 0; k < KB; ++k) acc[3 + c * KB + k] += jr * sp[k];
    }
  }
#pragma unroll
  for (int i = 0; i < 33; ++i) {
    float x = acc[i];
    for (int off = 32; off > 0; off >>= 1) x += __shfl_down(x, off);
    if ((threadIdx.x & 63) == 0) atomicAdd(&JJ[i], x);
  }
}

// ---------------------------------------------------------------- K2: Mc[n,c] = sum_m mean[m*384 + n*3+c]
__global__ __launch_bounds__(384) void k_mcreduce(
    const float* __restrict__ mean, float* __restrict__ Mc) {
  int t = threadIdx.x;
  float acc = 0.f;
#pragma unroll
  for (int mi = 0; mi < 8; ++mi)
    acc += mean[(size_t)(blockIdx.x * 8 + mi) * ROW384 + t];
  atomicAdd(&Mc[t], acc);
}

// ---------------------------------------------------------------- K3: single pass over pca_components
// block = (chunk, p): reads pc[p, m0:m0+32, :, :] (12288 floats, coalesced float4),
// computes U partial (sum over m, accumulated atomically into Ut[nc][p]),
// V2 (sum over n, written directly to V2t[mc][p]), cmean partial (dot with pca_mean).
__global__ __launch_bounds__(384) void k_pcpass(
    const float* __restrict__ pc, const float* __restrict__ mean,
    float* __restrict__ Ut, float* __restrict__ V2t, float* __restrict__ cmean) {
  __shared__ float tile[MT * LSTR];  // 49,664 B -> 3 blocks/CU
  const int t = threadIdx.x;
  const int pid = blockIdx.x & 127;        // consecutive blocks share the mean slice (L2)
  const int chunk = blockIdx.x >> 7;       // 0..21
  const int m0 = chunk * MT;
  const float* row = pc + (size_t)pid * D_TOT + (size_t)m0 * ROW384;
  const float* mrow = mean + (size_t)m0 * ROW384;

  float cm = 0.f;
#pragma unroll
  for (int i = 0; i < 8; ++i) {
    int f = 1536 * i + 4 * t;              // float offset of this float4
    float4 pv = *(const float4*)(row + f);
    float4 mv = *(const float4*)(mrow + f);
    cm += pv.x * mv.x + pv.y * mv.y + pv.z * mv.z + pv.w * mv.w;
    int m_l = 4 * i + t / 96;
    int col = (t % 96) * 4;
    *(float4*)(&tile[m_l * LSTR + col]) = pv;
  }
  __syncthreads();

  // U partial: fixed (n,c)=t, sum over the 32 m's of this tile
  float u = 0.f;
#pragma unroll
  for (int m = 0; m < MT; ++m) u += tile[m * LSTR + t];
  atomicAdd(&Ut[t * 128 + pid], u);

  // V2: fixed (m_l, c), sum over n
  if (t < 96) {
    int m_l = t / 3, c = t % 3;
    float vs = 0.f;
#pragma unroll 8
    for (int n = 0; n < N_A; ++n) vs += tile[m_l * LSTR + n * 3 + c];
    V2t[((size_t)(m0 + m_l) * 3 + c) * 128 + pid] = vs;
  }

  // cmean reduce across block
  __syncthreads();
  tile[t] = cm;
  __syncthreads();
  if (t < 128) tile[t] += tile[t + 128] + tile[t + 256];
  __syncthreads();
  for (int s = 64; s > 0; s >>= 1) {
    if (t < s) tile[t] += tile[t + s];
    __syncthreads();
  }
  if (t == 0) atomicAdd(&cmean[pid], tile[0]);
}

// ---------------------------------------------------------------- 3x3 SVD -> rotation (Kabsch w/ reflection fix)
__device__ inline double det3(const double A[3][3]) {
  return A[0][0] * (A[1][1] * A[2][2] - A[1][2] * A[2][1])
       - A[0][1] * (A[1][0] * A[2][2] - A[1][2] * A[2][0])
       + A[0][2] * (A[1][0] * A[2][1] - A[1][1] * A[2][0]);
}

__device__ void svd3_rotation(const float* S, float* Rout) {
  double M[3][3], B[3][3], Vv[3][3];
  for (int i = 0; i < 3; ++i)
    for (int j = 0; j < 3; ++j) M[i][j] = (double)S[i * 3 + j];
  for (int i = 0; i < 3; ++i)
    for (int j = 0; j < 3; ++j) {
      double a = 0;
      for (int k = 0; k < 3; ++k) a += M[k][i] * M[k][j];
      B[i][j] = a;
    }
  for (int i = 0; i < 3; ++i)
    for (int j = 0; j < 3; ++j) Vv[i][j] = (i == j) ? 1.0 : 0.0;
  const int PP[3] = {0, 0, 1}, QQ[3] = {1, 2, 2};
  for (int sweep = 0; sweep < 25; ++sweep) {
    double off = B[0][1] * B[0][1] + B[0][2] * B[0][2] + B[1][2] * B[1][2];
    double dg = B[0][0] * B[0][0] + B[1][1] * B[1][1] + B[2][2] * B[2][2];
    if (off <= 1e-28 * (dg + 1e-300)) break;
    for (int pr = 0; pr < 3; ++pr) {
      int p = PP[pr], q = QQ[pr];
      double apq = B[p][q];
      if (apq == 0.0) continue;
      double dd = (B[p][p] - B[q][q]) / (2.0 * apq);
      double tt = 1.0 / (fabs(dd) + sqrt(dd * dd + 1.0));
      if (dd < 0.0) tt = -tt;
      double cc = 1.0 / sqrt(tt * tt + 1.0), ss = tt * cc;
      B[p][p] += tt * apq;
      B[q][q] -= tt * apq;
      B[p][q] = B[q][p] = 0.0;
      int k = 3 - p - q;
      double Bkp = cc * B[k][p] + ss * B[k][q];
      double Bkq = -ss * B[k][p] + cc * B[k][q];
      B[k][p] = B[p][k] = Bkp;
      B[k][q] = B[q][k] = Bkq;
      for (int i = 0; i < 3; ++i) {
        double vip = cc * Vv[i][p] + ss * Vv[i][q];
        double viq = -ss * Vv[i][p] + cc * Vv[i][q];
        Vv[i][p] = vip;
        Vv[i][q] = viq;
      }
    }
  }
  double lam[3] = {B[0][0], B[1][1], B[2][2]};
  int o0 = 0, o1 = 1, o2 = 2, tp;
  if (lam[o0] < lam[o1]) { tp = o0; o0 = o1; o1 = tp; }
  if (lam[o0] < lam[o2]) { tp = o0; o0 = o2; o2 = tp; }
  if (lam[o1] < lam[o2]) { tp = o1; o1 = o2; o2 = tp; }
  int ord[3] = {o0, o1, o2};
  double sv[3], U[3][3], Vs[3][3];
  for (int j = 0; j < 3; ++j) {
    double l = lam[ord[j]];
    sv[j] = l > 0.0 ? sqrt(l) : 0.0;
    for (int i = 0; i < 3; ++i) Vs[i][j] = Vv[i][ord[j]];
  }
  for (int j = 0; j < 3; ++j) {
    double vx = Vs[0][j], vy = Vs[1][j], vz = Vs[2][j];
    double ux = M[0][0] * vx + M[0][1] * vy + M[0][2] * vz;
    double uy = M[1][0] * vx + M[1][1] * vy + M[1][2] * vz;
    double uz = M[2][0] * vx + M[2][1] * vy + M[2][2] * vz;
    double sj = sv[j];
    if (sj > 1e-12 * (sv[0] + 1e-300)) {
      U[0][j] = ux / sj; U[1][j] = uy / sj; U[2][j] = uz / sj;
    } else if (j == 2) {
      double cx = U[1][0] * U[2][1] - U[2][0] * U[1][1];
      double cy = U[2][0] * U[0][1] - U[0][0] * U[2][1];
      double cz = U[0][0] * U[1][1] - U[1][0] * U[0][1];
      double nn = sqrt(cx * cx + cy * cy + cz * cz);
      if (nn < 1e-300) { cx = 0; cy = 0; cz = 1; nn = 1; }
      U[0][2] = cx / nn; U[1][2] = cy / nn; U[2][2] = cz / nn;
    } else {
      U[0][j] = (j == 0) ? 1.0 : 0.0;
      U[1][j] = (j == 1) ? 1.0 : 0.0;
      U[2][j] = 0.0;
    }
  }
  double dsgn = (det3(U) * det3(Vs)) < 0.0 ? -1.0 : 1.0;
  for (int i = 0; i < 3; ++i)
    for (int j = 0; j < 3; ++j)
      Rout[i * 3 + j] = (float)(U[i][0] * Vs[j][0] + U[i][1] * Vs[j][1] +
                                dsgn * U[i][2] * Vs[j][2]);
}

// ---------------------------------------------------------------- K4: per-batch (one block per b)
__global__ __launch_bounds__(384) void k_batch(
    const float* __restrict__ betas, const float* __restrict__ rot,
    const float* __restrict__ trans, const float* __restrict__ org,
    const float* __restrict__ vt, const float* __restrict__ sd,
    const int* __restrict__ anch, const float* __restrict__ JJ,
    const float* __restrict__ cmean, const float* __restrict__ Mc,
    const float* __restrict__ Ut, const float* __restrict__ V2t,
    float* __restrict__ out) {
  const int b = blockIdx.x, t = threadIdx.x;
  __shared__ float saL[2112], objL[384], orgL[384], A[384], red[384], gammaL[128];
  __shared__ float betasL[10], rotL[9], transL[3], J0L[3], cQ[3], smat[9], RL[9];

  // stage 0: small loads (disjoint thread ranges) + org
  if (t < 10) betasL[t] = betas[b * 10 + t];
  else if (t >= 16 && t < 25) rotL[t - 16] = rot[b * 9 + (t - 16)];
  else if (t >= 32 && t < 35) transL[t - 32] = trans[b * 3 + (t - 32)];
  orgL[t] = org[(size_t)b * 384 + t];
  __syncthreads();

  // stage 1: J0, obj transform, centerQ
  if (t < 3) {
    float j0 = JJ[t];
#pragma unroll
    for (int k = 0; k < KB; ++k) j0 += betasL[k] * JJ[3 + t * KB + k];
    J0L[t] = j0;
    float s = 0.f;
    for (int n = 0; n < N_A; ++n) s += orgL[n * 3 + t];
    cQ[t] = s * (1.f / 128.f);
  }
  {
    int n = t / 3, d = t % 3;
    objL[t] = orgL[n * 3 + 0] * rotL[d * 3 + 0] +
              orgL[n * 3 + 1] * rotL[d * 3 + 1] +
              orgL[n * 3 + 2] * rotL[d * 3 + 2] + transL[d];
  }
  __syncthreads();

  // stage 2: smpl anchors  sa[m,c] = vt[a,c] + betas.sd[a,c,:] - J0[c]
  for (int e = t; e < 2112; e += 384) {
    int m = e / 3, c = e % 3;
    int a = anch[m];
    const float* sp = sd + ((size_t)a * 3 + c) * KB;
    float val = vt[a * 3 + c];
#pragma unroll
    for (int k = 0; k < KB; ++k) val += betasL[k] * sp[k];
    saL[e] = val - J0L[c];
  }
  __syncthreads();

  // stage 3: gamma[p] = sum_nc obj*Ut - sum_mc sa*V2t - cmean   (3 e-groups x 128 p)
  {
    int g = t >> 7, p = t & 127;
    int e0 = g * 832, e1 = e0 + 832;
    float s = 0.f;
    int e = e0, eb = (e1 < 384) ? e1 : 384;
#pragma unroll 4
    for (; e < eb; ++e) s += objL[e] * Ut[(size_t)e * 128 + p];
#pragma unroll 4
    for (; e < e1; ++e) s -= saL[e - 384] * V2t[(size_t)(e - 384) * 128 + p];
    red[t] = s;
  }
  __syncthreads();
  if (t < 128) {
    float g = red[t] + red[t + 128] + red[t + 256] - cmean[t];
    gammaL[t] = g;
    out[b * 128 + t] = g;  // output 0
  }
  __syncthreads();

  // stage 4: A[n,c] = Mc[n,c] + sum_p gamma[p]*U[p,n,c]
  {
    const float4* up4 = (const float4*)(Ut + (size_t)t * 128);
    float gs = 0.f;
#pragma unroll 8
    for (int i = 0; i < 32; ++i) {
      float4 u4 = up4[i];
      gs += gammaL[4 * i] * u4.x + gammaL[4 * i + 1] * u4.y +
            gammaL[4 * i + 2] * u4.z + gammaL[4 * i + 3] * u4.w;
    }
    A[t] = Mc[t] + gs;
  }
  __syncthreads();

  // stage 5: svd_mat[c,d] = sum_n A[n,c]*(org[n,d]-cQ[d])
  if (t < 9) {
    int c = t / 3, d = t % 3;
    float s = 0.f, cq = cQ[d];
    for (int n = 0; n < N_A; ++n) s += A[n * 3 + c] * (orgL[n * 3 + d] - cq);
    smat[t] = s;
  }
  __syncthreads();
  if (t == 0) svd3_rotation(smat, RL);
  __syncthreads();
  if (t < 9) out[8192 + b * 9 + t] = RL[t];  // output 1
  if (t < 3) {
    float s1 = 0.f;
    for (int m = 0; m < M_A; ++m) s1 += saL[m * 3 + t];
    float s2 = 0.f;
    for (int n = 0; n < N_A; ++n) s2 += A[n * 3 + t];
    float meanP = s1 * (1.f / 704.f) + s2 * (1.f / 90112.f);
    float rq = RL[t * 3 + 0] * cQ[0] + RL[t * 3 + 1] * cQ[1] + RL[t * 3 + 2] * cQ[2];
    out[8768 + b * 3 + t] = meanP - rq;  // output 2
  }
}

// ----------------------------------------------------------------
extern "C" void kernel_launch(void* const* d_in, const int* in_sizes, int n_in,
                              void* d_out, int out_size, void* d_ws, size_t ws_size,
                              hipStream_t stream) {
  const float* betas = (const float*)d_in[0];
  const float* rot   = (const float*)d_in[1];
  const float* trans = (const float*)d_in[2];
  const float* org   = (const float*)d_in[3];
  const float* vt    = (const float*)d_in[4];
  const float* sd    = (const float*)d_in[5];
  const float* Jr    = (const float*)d_in[6];
  const float* mean  = (const float*)d_in[7];
  const float* pc    = (const float*)d_in[8];
  const int*   anch  = (const int*)d_in[9];
  float* out = (float*)d_out;
  float* ws  = (float*)d_ws;
  if (ws_size < (size_t)WS_TOTAL * sizeof(float)) return;  // need ~1.28 MB scratch

  float* JJ    = ws + WS_JJ;
  float* cmean = ws + WS_CMEAN;
  float* Mc    = ws + WS_MC;
  float* Ut    = ws + WS_UT;
  float* V2t   = ws + WS_V2T;

  hipMemsetAsync(ws, 0, (size_t)WS_ZEROF * sizeof(float), stream);
  k_jreduce<<<64, 256, 0, stream>>>(Jr, vt, sd, JJ);
  k_mcreduce<<<88, 384, 0, stream>>>(mean, Mc);
  k_pcpass<<<NCHUNK * 128, 384, 0, stream>>>(pc, mean, Ut, V2t, cmean);
  k_batch<<<64, 384, 0, stream>>>(betas, rot, trans, org, vt, sd, anch,
                                  JJ, cmean, Mc, Ut, V2t, out);
}

// Round 2
// 313.645 us; speedup vs baseline: 1.2773x; 1.2773x over previous
//
#include <hip/hip_runtime.h>

// Problem constants
#define V_CNT   10475
#define M_A     704
#define N_A     128
#define KB      10
#define D_TOT   270336       // 704*128*3
#define ROW384  384          // 128*3 floats per m-row of a pc row
#define NCHUNK  22           // 704 / MT
#define MT      32           // m-tile in k_pcpass
#define LSTR    388          // LDS row stride: 388%32=4 breaks bank conflicts, %4==0 keeps float4 alignment

// ws layout (float offsets)
#define WS_JJ     0          // 33: Jv[3], JB[3][10]
#define WS_CMEAN  64         // 128
#define WS_MC     192        // 384
#define WS_V2C    576        // 3*128 = 384   V2c[c][p] = sum_m V2[p][m][c]
#define WS_SASUM  960        // 64*3          sum_m sa0[b][m][c]
#define WS_GWS    1152       // 64*128 = 8192 gamma partials
#define WS_WT     9344       // 2496*128 = 319488: rows<384 = Ut[nc][p] (atomic), rows>=384 = -V2[e][p]
#define WS_X      328832     // 64*2496: [obj(384); sa0(2112)] per b
#define WS_TOTAL  488576     // floats (1.95 MB)
#define WS_ZEROF  58496      // zero JJ..Wt's Ut rows (all atomic targets)

#define NJ_BLK 28
#define NM_BLK 88
#define NP_BLK 64

// ---------------------------------------------------------------- K1: fused precompute
// blocks [0,28): J-reduce; [28,116): Mc-reduce; [116,180): per-b prep (obj + sa0 + saSum)
__global__ __launch_bounds__(384) void k_pre(
    const float* __restrict__ Jr, const float* __restrict__ vt,
    const float* __restrict__ sd, const float* __restrict__ mean,
    const float* __restrict__ betas, const float* __restrict__ rot,
    const float* __restrict__ trans, const float* __restrict__ org,
    const int* __restrict__ anch,
    float* __restrict__ JJ, float* __restrict__ Mc,
    float* __restrict__ X, float* __restrict__ saSum) {
  __shared__ float orgL[384];
  __shared__ float red[384];
  __shared__ float small[24];  // 0..9 betas, 10..18 rot, 19..21 trans
  const int blk = blockIdx.x, t = threadIdx.x;

  if (blk < NJ_BLK) {
    // ---- J row-0 reduction: Jv[3], JB[3][10]
    float acc[33];
#pragma unroll
    for (int i = 0; i < 33; ++i) acc[i] = 0.f;
    int v = blk * 384 + t;
    if (v < V_CNT) {
      float jr = Jr[v];
#pragma unroll
      for (int c = 0; c < 3; ++c) {
        acc[c] += jr * vt[v * 3 + c];
        const float* sp = sd + ((size_t)v * 3 + c) * KB;
#pragma unroll
        for (int k = 0; k < KB; ++k) acc[3 + c * KB + k] += jr * sp[k];
      }
    }
#pragma unroll
    for (int i = 0; i < 33; ++i) {
      float x = acc[i];
      for (int off = 32; off > 0; off >>= 1) x += __shfl_down(x, off);
      if ((t & 63) == 0) atomicAdd(&JJ[i], x);
    }
  } else if (blk < NJ_BLK + NM_BLK) {
    // ---- Mc[n,c] = sum_m mean
    int j = blk - NJ_BLK;
    float a = 0.f;
#pragma unroll
    for (int mi = 0; mi < 8; ++mi)
      a += mean[(size_t)(j * 8 + mi) * ROW384 + t];
    atomicAdd(&Mc[t], a);
  } else {
    // ---- per-batch prep
    const int b = blk - (NJ_BLK + NM_BLK);
    if (t < 10) small[t] = betas[b * 10 + t];
    else if (t >= 10 && t < 19) small[t] = rot[b * 9 + (t - 10)];
    else if (t >= 19 && t < 22) small[t] = trans[b * 3 + (t - 19)];
    orgL[t] = org[(size_t)b * 384 + t];
    __syncthreads();
    // obj[n,d] = sum_c org[n,c]*rot[d,c] + trans[d]  -> X rows [0,384)
    {
      int n = t / 3, d = t % 3;
      X[(size_t)b * 2496 + t] =
          orgL[n * 3 + 0] * small[10 + d * 3 + 0] +
          orgL[n * 3 + 1] * small[10 + d * 3 + 1] +
          orgL[n * 3 + 2] * small[10 + d * 3 + 2] + small[19 + d];
    }
    // sa0[m,c] = vt + betas.sd (NO J0 subtraction) -> X rows [384,2496)
    float ps = 0.f;  // partial of sum_m sa0[m, c=t%3] (384%3==0 so c is fixed per thread)
    for (int e = t; e < 2112; e += 384) {
      int m = e / 3, c = e % 3;
      int a = anch[m];
      const float* sp = sd + ((size_t)a * 3 + c) * KB;
      float val = vt[a * 3 + c];
#pragma unroll
      for (int k = 0; k < KB; ++k) val += small[k] * sp[k];
      X[(size_t)b * 2496 + 384 + e] = val;
      ps += val;
    }
    red[t] = ps;
    __syncthreads();
    if (t < 3) {
      float s = 0.f;
#pragma unroll 8
      for (int j = 0; j < 128; ++j) s += red[t + 3 * j];
      saSum[b * 3 + t] = s;
    }
  }
}

// ---------------------------------------------------------------- K2: single pass over pca_components
__global__ __launch_bounds__(384) void k_pcpass(
    const float* __restrict__ pc, const float* __restrict__ mean,
    float* __restrict__ Wt, float* __restrict__ V2c, float* __restrict__ cmean) {
  __shared__ float tile[MT * LSTR];  // 49,664 B -> 3 blocks/CU
  const int t = threadIdx.x;
  const int pid = blockIdx.x & 127;
  const int chunk = blockIdx.x >> 7;  // 0..21
  const int m0 = chunk * MT;
  const float* row = pc + (size_t)pid * D_TOT + (size_t)m0 * ROW384;
  const float* mrow = mean + (size_t)m0 * ROW384;

  float cm = 0.f;
#pragma unroll
  for (int i = 0; i < 8; ++i) {
    int f = 1536 * i + 4 * t;
    float4 pv = *(const float4*)(row + f);
    float4 mv = *(const float4*)(mrow + f);
    cm += pv.x * mv.x + pv.y * mv.y + pv.z * mv.z + pv.w * mv.w;
    int m_l = 4 * i + t / 96;
    int col = (t % 96) * 4;
    *(float4*)(&tile[m_l * LSTR + col]) = pv;
  }
  __syncthreads();  // S1

  // U partial: fixed (n,c)=t, sum over 32 m -> atomic into Wt row t
  float u = 0.f;
#pragma unroll
  for (int m = 0; m < MT; ++m) u += tile[m * LSTR + t];
  atomicAdd(&Wt[(size_t)t * 128 + pid], u);

  // V2 partial: all 384 threads. t = grp*96 + (m_l*3+c), each sums 32 n's
  float vsp = 0.f;
  {
    int grp = t / 96, mc = t % 96, m_l = mc / 3, c = mc % 3;
    const float* tp = &tile[m_l * LSTR + c];
#pragma unroll 8
    for (int j = 0; j < 32; ++j) vsp += tp[(grp * 32 + j) * 3];
  }
  __syncthreads();  // S2: all tile reads done
  tile[t] = vsp;
  // cmean wave-reduce (no LDS tree)
  {
    float x = cm;
    for (int off = 32; off > 0; off >>= 1) x += __shfl_down(x, off);
    if ((t & 63) == 0) tile[384 + (t >> 6)] = x;
  }
  __syncthreads();  // S3
  if (t < 96) {
    float vs = tile[t] + tile[96 + t] + tile[192 + t] + tile[288 + t];
    int m_l = t / 3, c = t % 3;
    Wt[(size_t)(384 + (m0 + m_l) * 3 + c) * 128 + pid] = -vs;  // W row = -V2
    tile[400 + t] = vs;
  }
  if (t == 0) {
    float s = 0.f;
#pragma unroll
    for (int w = 0; w < 6; ++w) s += tile[384 + w];
    atomicAdd(&cmean[pid], s);
  }
  __syncthreads();  // S4
  if (t < 3) {
    float sv = 0.f;
#pragma unroll 8
    for (int j = 0; j < 32; ++j) sv += tile[400 + t + 3 * j];
    atomicAdd(&V2c[t * 128 + pid], sv);
  }
}

// ---------------------------------------------------------------- K3: gamma partial dots
// grid = 64 b * 8 slices; blockIdx = b*8 + slice -> XCD x sees only slice x (L2 locality)
__global__ __launch_bounds__(256) void k_gamma(
    const float* __restrict__ X, const float* __restrict__ Wt,
    float* __restrict__ gWS) {
  __shared__ float XL[312];
  const int b = blockIdx.x >> 3, sl = blockIdx.x & 7, t = threadIdx.x;
  const int e0 = sl * 312;
  for (int i = t; i < 312; i += 256) XL[i] = X[(size_t)b * 2496 + e0 + i];
  __syncthreads();
  const int p = t & 127, g = t >> 7;
  const float* W = Wt + (size_t)(e0 + g * 156) * 128 + p;
  const float* xr = XL + g * 156;
  float s = 0.f;
#pragma unroll 12
  for (int i = 0; i < 156; ++i) s += xr[i] * W[(size_t)i * 128];
  atomicAdd(&gWS[b * 128 + p], s);
}

// ---------------------------------------------------------------- 3x3 SVD -> rotation (Kabsch w/ reflection fix)
__device__ inline double det3(const double A[3][3]) {
  return A[0][0] * (A[1][1] * A[2][2] - A[1][2] * A[2][1])
       - A[0][1] * (A[1][0] * A[2][2] - A[1][2] * A[2][0])
       + A[0][2] * (A[1][0] * A[2][1] - A[1][1] * A[2][0]);
}

__device__ void svd3_rotation(const float* S, float* Rout) {
  double M[3][3], B[3][3], Vv[3][3];
  for (int i = 0; i < 3; ++i)
    for (int j = 0; j < 3; ++j) M[i][j] = (double)S[i * 3 + j];
  for (int i = 0; i < 3; ++i)
    for (int j = 0; j < 3; ++j) {
      double a = 0;
      for (int k = 0; k < 3; ++k) a += M[k][i] * M[k][j];
      B[i][j] = a;
    }
  for (int i = 0; i < 3; ++i)
    for (int j = 0; j < 3; ++j) Vv[i][j] = (i == j) ? 1.0 : 0.0;
  const int PP[3] = {0, 0, 1}, QQ[3] = {1, 2, 2};
  for (int sweep = 0; sweep < 25; ++sweep) {
    double off = B[0][1] * B[0][1] + B[0][2] * B[0][2] + B[1][2] * B[1][2];
    double dg = B[0][0] * B[0][0] + B[1][1] * B[1][1] + B[2][2] * B[2][2];
    if (off <= 1e-28 * (dg + 1e-300)) break;
    for (int pr = 0; pr < 3; ++pr) {
      int p = PP[pr], q = QQ[pr];
      double apq = B[p][q];
      if (apq == 0.0) continue;
      double dd = (B[p][p] - B[q][q]) / (2.0 * apq);
      double tt = 1.0 / (fabs(dd) + sqrt(dd * dd + 1.0));
      if (dd < 0.0) tt = -tt;
      double cc = 1.0 / sqrt(tt * tt + 1.0), ss = tt * cc;
      B[p][p] += tt * apq;
      B[q][q] -= tt * apq;
      B[p][q] = B[q][p] = 0.0;
      int k = 3 - p - q;
      double Bkp = cc * B[k][p] + ss * B[k][q];
      double Bkq = -ss * B[k][p] + cc * B[k][q];
      B[k][p] = B[p][k] = Bkp;
      B[k][q] = B[q][k] = Bkq;
      for (int i = 0; i < 3; ++i) {
        double vip = cc * Vv[i][p] + ss * Vv[i][q];
        double viq = -ss * Vv[i][p] + cc * Vv[i][q];
        Vv[i][p] = vip;
        Vv[i][q] = viq;
      }
    }
  }
  double lam[3] = {B[0][0], B[1][1], B[2][2]};
  int o0 = 0, o1 = 1, o2 = 2, tp;
  if (lam[o0] < lam[o1]) { tp = o0; o0 = o1; o1 = tp; }
  if (lam[o0] < lam[o2]) { tp = o0; o0 = o2; o2 = tp; }
  if (lam[o1] < lam[o2]) { tp = o1; o1 = o2; o2 = tp; }
  int ord[3] = {o0, o1, o2};
  double sv[3], U[3][3], Vs[3][3];
  for (int j = 0; j < 3; ++j) {
    double l = lam[ord[j]];
    sv[j] = l > 0.0 ? sqrt(l) : 0.0;
    for (int i = 0; i < 3; ++i) Vs[i][j] = Vv[i][ord[j]];
  }
  for (int j = 0; j < 3; ++j) {
    double vx = Vs[0][j], vy = Vs[1][j], vz = Vs[2][j];
    double ux = M[0][0] * vx + M[0][1] * vy + M[0][2] * vz;
    double uy = M[1][0] * vx + M[1][1] * vy + M[1][2] * vz;
    double uz = M[2][0] * vx + M[2][1] * vy + M[2][2] * vz;
    double sj = sv[j];
    if (sj > 1e-12 * (sv[0] + 1e-300)) {
      U[0][j] = ux / sj; U[1][j] = uy / sj; U[2][j] = uz / sj;
    } else if (j == 2) {
      double cx = U[1][0] * U[2][1] - U[2][0] * U[1][1];
      double cy = U[2][0] * U[0][1] - U[0][0] * U[2][1];
      double cz = U[0][0] * U[1][1] - U[1][0] * U[0][1];
      double nn = sqrt(cx * cx + cy * cy + cz * cz);
      if (nn < 1e-300) { cx = 0; cy = 0; cz = 1; nn = 1; }
      U[0][2] = cx / nn; U[1][2] = cy / nn; U[2][2] = cz / nn;
    } else {
      U[0][j] = (j == 0) ? 1.0 : 0.0;
      U[1][j] = (j == 1) ? 1.0 : 0.0;
      U[2][j] = 0.0;
    }
  }
  double dsgn = (det3(U) * det3(Vs)) < 0.0 ? -1.0 : 1.0;
  for (int i = 0; i < 3; ++i)
    for (int j = 0; j < 3; ++j)
      Rout[i * 3 + j] = (float)(U[i][0] * Vs[j][0] + U[i][1] * Vs[j][1] +
                                dsgn * U[i][2] * Vs[j][2]);
}

// ---------------------------------------------------------------- K4: finalize per batch
__global__ __launch_bounds__(384) void k_finish(
    const float* __restrict__ betas, const float* __restrict__ org,
    const float* __restrict__ JJ, const float* __restrict__ cmean,
    const float* __restrict__ Mc, const float* __restrict__ V2c,
    const float* __restrict__ saSum, const float* __restrict__ gWS,
    const float* __restrict__ Wt, float* __restrict__ out) {
  const int b = blockIdx.x, t = threadIdx.x;
  __shared__ float orgL[384], A[384], gammaL[128];
  __shared__ float betasL[10], J0L[3], cQ[3], smat[9], RL[9];

  if (t < 10) betasL[t] = betas[b * 10 + t];
  orgL[t] = org[(size_t)b * 384 + t];
  __syncthreads();
  if (t < 3) {
    float j0 = JJ[t];
#pragma unroll
    for (int k = 0; k < KB; ++k) j0 += betasL[k] * JJ[3 + t * KB + k];
    J0L[t] = j0;
    float s = 0.f;
    for (int n = 0; n < N_A; ++n) s += orgL[n * 3 + t];
    cQ[t] = s * (1.f / 128.f);
  }
  __syncthreads();

  // gamma finalize: + J0.V2c (restores the -J0 part of sa) - cmean
  if (t < 128) {
    float g = gWS[b * 128 + t] + J0L[0] * V2c[t] + J0L[1] * V2c[128 + t] +
              J0L[2] * V2c[256 + t] - cmean[t];
    gammaL[t] = g;
    out[b * 128 + t] = g;  // output 0
  }
  __syncthreads();

  // A[n,c] = Mc + sum_p gamma[p]*Ut[p][n,c]  (Ut = Wt rows < 384, p-contiguous)
  {
    const float4* up4 = (const float4*)(Wt + (size_t)t * 128);
    float gs = 0.f;
#pragma unroll 8
    for (int i = 0; i < 32; ++i) {
      float4 u4 = up4[i];
      gs += gammaL[4 * i] * u4.x + gammaL[4 * i + 1] * u4.y +
            gammaL[4 * i + 2] * u4.z + gammaL[4 * i + 3] * u4.w;
    }
    A[t] = Mc[t] + gs;
  }
  __syncthreads();

  if (t < 9) {
    int c = t / 3, d = t % 3;
    float s = 0.f, cq = cQ[d];
    for (int n = 0; n < N_A; ++n) s += A[n * 3 + c] * (orgL[n * 3 + d] - cq);
    smat[t] = s;
  }
  __syncthreads();
  if (t == 0) svd3_rotation(smat, RL);
  __syncthreads();
  if (t < 9) out[8192 + b * 9 + t] = RL[t];  // output 1
  if (t < 3) {
    float s2 = 0.f;
    for (int n = 0; n < N_A; ++n) s2 += A[n * 3 + t];
    float meanP = saSum[b * 3 + t] * (1.f / 704.f) - J0L[t] + s2 * (1.f / 90112.f);
    float rq = RL[t * 3 + 0] * cQ[0] + RL[t * 3 + 1] * cQ[1] + RL[t * 3 + 2] * cQ[2];
    out[8768 + b * 3 + t] = meanP - rq;  // output 2
  }
}

// ----------------------------------------------------------------
extern "C" void kernel_launch(void* const* d_in, const int* in_sizes, int n_in,
                              void* d_out, int out_size, void* d_ws, size_t ws_size,
                              hipStream_t stream) {
  const float* betas = (const float*)d_in[0];
  const float* rot   = (const float*)d_in[1];
  const float* trans = (const float*)d_in[2];
  const float* org   = (const float*)d_in[3];
  const float* vt    = (const float*)d_in[4];
  const float* sd    = (const float*)d_in[5];
  const float* Jr    = (const float*)d_in[6];
  const float* mean  = (const float*)d_in[7];
  const float* pc    = (const float*)d_in[8];
  const int*   anch  = (const int*)d_in[9];
  float* out = (float*)d_out;
  float* ws  = (float*)d_ws;
  if (ws_size < (size_t)WS_TOTAL * sizeof(float)) return;  // need ~1.95 MB scratch

  float* JJ    = ws + WS_JJ;
  float* cmean = ws + WS_CMEAN;
  float* Mc    = ws + WS_MC;
  float* V2c   = ws + WS_V2C;
  float* saSum = ws + WS_SASUM;
  float* gWS   = ws + WS_GWS;
  float* Wt    = ws + WS_WT;
  float* X     = ws + WS_X;

  hipMemsetAsync(ws, 0, (size_t)WS_ZEROF * sizeof(float), stream);
  k_pre<<<NJ_BLK + NM_BLK + NP_BLK, 384, 0, stream>>>(
      Jr, vt, sd, mean, betas, rot, trans, org, anch, JJ, Mc, X, saSum);
  k_pcpass<<<NCHUNK * 128, 384, 0, stream>>>(pc, mean, Wt, V2c, cmean);
  k_gamma<<<64 * 8, 256, 0, stream>>>(X, Wt, gWS);
  k_finish<<<64, 384, 0, stream>>>(betas, org, JJ, cmean, Mc, V2c, saSum, gWS,
                                   Wt, out);
}